// Round 1
// baseline (16910.960 us; speedup 1.0000x reference)
//
#include <hip/hip_runtime.h>

// ---------------------------------------------------------------------------
// LanguageModel: embed -> LSTM(1024) x2 -> last-step logits(32000) -> softmax
// B=64, S=512, E=512, H=1024, G=4H=4096, V=32000
//
// Strategy (round 0): all big matmuls as bf16 MFMA (16x16x32), fp32 accum,
// fp32 state/nonlinearities. Weights pre-packed into MFMA B-fragment layout
// each launch; activations written directly in MFMA A-fragment layout.
// Recurrence: 512 launches/layer, 64 blocks x 256 thr, wave = one gate.
// Workspace use: ~474 MB.
// ---------------------------------------------------------------------------

#define BB 64
#define SS 512
#define EE 512
#define HH 1024
#define GG 4096
#define VV 32000

using bf16x8 = __attribute__((ext_vector_type(8))) __bf16;
using f32x4  = __attribute__((ext_vector_type(4))) float;

__device__ __forceinline__ unsigned short f2bf(float f) {
    unsigned u = __float_as_uint(f);
    unsigned r = u + 0x7FFFu + ((u >> 16) & 1u);   // RNE
    return (unsigned short)(r >> 16);
}
__device__ __forceinline__ float bf2f(unsigned short u) {
    return __uint_as_float(((unsigned)u) << 16);
}
__device__ __forceinline__ float sigm(float x) {
    return 1.0f / (1.0f + expf(-x));
}

// Packed-B layout: elem(nt, kt, lane, j) = B[kt*32 + (lane>>4)*8 + j][nt*16 + (lane&15)]
// stored at ((nt*KT + kt)*64 + lane)*8 + j
__global__ void pack_b(const float* __restrict__ B, unsigned short* __restrict__ out,
                       int KT, int N) {
    int bid = blockIdx.x;          // = nt*KT + kt
    int lane = threadIdx.x;
    int nt = bid / KT, kt = bid % KT;
    int k = kt * 32 + ((lane >> 4) << 3);
    int n = nt * 16 + (lane & 15);
    size_t base = ((size_t)bid * 64 + lane) * 8;
    #pragma unroll
    for (int j = 0; j < 8; ++j)
        out[base + j] = f2bf(B[(size_t)(k + j) * N + n]);
}

// Packed-A layout: elem(mt, kt, lane, j) = A[mt*16 + (lane&15)][kt*32 + (lane>>4)*8 + j]
// Embedding gather written directly in packed-A form (M=32768 rows, K=512).
__global__ void embed_pack(const int* __restrict__ x, const float* __restrict__ tab,
                           unsigned short* __restrict__ out) {
    int bid = blockIdx.x;          // = mt*16 + kt  (KT=16)
    int lane = threadIdx.x;
    int mt = bid >> 4, kt = bid & 15;
    int m = mt * 16 + (lane & 15); // row = b*SS + s
    int idx = x[m];
    int kb = kt * 32 + ((lane >> 4) << 3);
    size_t base = ((size_t)bid * 64 + lane) * 8;
    const float* src = tab + (size_t)idx * EE + kb;
    #pragma unroll
    for (int j = 0; j < 8; ++j)
        out[base + j] = f2bf(src[j]);
}

// C[M,N] = A@B + bias. Block: 64 rows x 64 cols, 4 waves (one 16-col tile each).
template<int BF16OUT>
__global__ __launch_bounds__(256) void gemm_bias(
    const unsigned short* __restrict__ Ap, const unsigned short* __restrict__ Bp,
    const float* __restrict__ bias, void* __restrict__ Cout, int N, int KT) {
    const int tid = threadIdx.x, lane = tid & 63, w = tid >> 6;
    const int ntg = blockIdx.x * 4 + w;   // global n-tile
    const int m0t = blockIdx.y * 4;       // base m-tile
    const bf16x8* Av = reinterpret_cast<const bf16x8*>(Ap);
    const bf16x8* Bv = reinterpret_cast<const bf16x8*>(Bp);
    f32x4 acc[4] = {{0.f,0.f,0.f,0.f},{0.f,0.f,0.f,0.f},{0.f,0.f,0.f,0.f},{0.f,0.f,0.f,0.f}};
    for (int kt = 0; kt < KT; ++kt) {
        bf16x8 b = Bv[((size_t)ntg * KT + kt) * 64 + lane];
        #pragma unroll
        for (int mt = 0; mt < 4; ++mt) {
            bf16x8 a = Av[((size_t)(m0t + mt) * KT + kt) * 64 + lane];
            acc[mt] = __builtin_amdgcn_mfma_f32_16x16x32_bf16(a, b, acc[mt], 0, 0, 0);
        }
    }
    const int col = ntg * 16 + (lane & 15);
    const int rq = (lane >> 4) << 2;
    const float bb = bias[col];
    #pragma unroll
    for (int mt = 0; mt < 4; ++mt)
        #pragma unroll
        for (int i = 0; i < 4; ++i) {
            int row = (m0t + mt) * 16 + rq + i;
            float v = acc[mt][i] + bb;
            if (BF16OUT) ((unsigned short*)Cout)[(size_t)row * N + col] = f2bf(v);
            else         ((float*)Cout)[(size_t)row * N + col] = v;
        }
}

__global__ void zero_state(float* __restrict__ c, unsigned short* __restrict__ h0) {
    int i = blockIdx.x * 256 + threadIdx.x;
    for (; i < BB * HH; i += 64 * 256) { c[i] = 0.f; h0[i] = 0; }
}

// One LSTM timestep. Grid: 64 blocks (16 h-cols each), 256 thr (wave w = gate w).
// hin/hout: packed-A layout of h [M=64, K=1024]. h1A (layer 0 only): packed-A
// rows m = b*SS + t for the layer-1 input GEMM.
__global__ __launch_bounds__(256) void lstm_step(
    const unsigned short* __restrict__ x4, const unsigned short* __restrict__ whp,
    const unsigned short* __restrict__ hin, unsigned short* __restrict__ hout,
    float* __restrict__ cbuf, unsigned short* __restrict__ h1A, int t) {
    __shared__ float g_lds[4 * 64 * 16];
    const int tid = threadIdx.x, lane = tid & 63, w = tid >> 6;
    const int bx = blockIdx.x;
    const int KT = HH / 32;  // 32
    const bf16x8* hv = reinterpret_cast<const bf16x8*>(hin);
    const bf16x8* bv = reinterpret_cast<const bf16x8*>(whp);
    f32x4 acc[4] = {{0.f,0.f,0.f,0.f},{0.f,0.f,0.f,0.f},{0.f,0.f,0.f,0.f},{0.f,0.f,0.f,0.f}};
    const int ntg = w * 64 + bx;  // gate-col tile in Wh (N=4096)
    for (int kt = 0; kt < KT; ++kt) {
        bf16x8 b = bv[((size_t)ntg * KT + kt) * 64 + lane];
        #pragma unroll
        for (int mt = 0; mt < 4; ++mt) {
            bf16x8 a = hv[((size_t)mt * KT + kt) * 64 + lane];
            acc[mt] = __builtin_amdgcn_mfma_f32_16x16x32_bf16(a, b, acc[mt], 0, 0, 0);
        }
    }
    const int col = lane & 15;
    const int rq = (lane >> 4) << 2;
    const int gcol = w * HH + bx * 16 + col;
    #pragma unroll
    for (int mt = 0; mt < 4; ++mt)
        #pragma unroll
        for (int i = 0; i < 4; ++i) {
            int row = mt * 16 + rq + i;  // batch index
            float xv = bf2f(x4[((size_t)row * SS + t) * GG + gcol]);
            g_lds[(w * 64 + row) * 16 + col] = acc[mt][i] + xv;
        }
    __syncthreads();
    #pragma unroll
    for (int e = 0; e < 4; ++e) {
        int flat = e * 256 + tid;        // 0..1023 = 64 rows x 16 cols
        int row = flat >> 4, c_ = flat & 15;
        int jg = bx * 16 + c_;           // h column
        float gi = g_lds[(0 * 64 + row) * 16 + c_];
        float gf = g_lds[(1 * 64 + row) * 16 + c_];
        float gg = g_lds[(2 * 64 + row) * 16 + c_];
        float go = g_lds[(3 * 64 + row) * 16 + c_];
        float co = cbuf[row * HH + jg];
        float cn = sigm(gf) * co + sigm(gi) * tanhf(gg);
        cbuf[row * HH + jg] = cn;
        float h = sigm(go) * tanhf(cn);
        unsigned short hb = f2bf(h);
        // packed-A (M=64,K=1024): ((mt*32+kt)*64 + ((k%32)/8)*16 + m%16)*8 + k%8
        hout[(((size_t)(row >> 4) * 32 + (jg >> 5)) * 64 + ((jg >> 3) & 3) * 16 + (row & 15)) * 8 + (jg & 7)] = hb;
        if (h1A) {
            int m = row * SS + t;
            h1A[(((size_t)(m >> 4) * 32 + (jg >> 5)) * 64 + ((jg >> 3) & 3) * 16 + (m & 15)) * 8 + (jg & 7)] = hb;
        }
    }
}

__global__ __launch_bounds__(256) void softmax_rows(const float* __restrict__ logits,
                                                    float* __restrict__ out) {
    __shared__ float red[256];
    int r = blockIdx.x, tid = threadIdx.x;
    const float* L = logits + (size_t)r * VV;
    float m = -1e30f;
    for (int i = tid; i < VV; i += 256) m = fmaxf(m, L[i]);
    red[tid] = m; __syncthreads();
    for (int s = 128; s > 0; s >>= 1) { if (tid < s) red[tid] = fmaxf(red[tid], red[tid + s]); __syncthreads(); }
    m = red[0]; __syncthreads();
    float sum = 0.f;
    for (int i = tid; i < VV; i += 256) sum += expf(L[i] - m);
    red[tid] = sum; __syncthreads();
    for (int s = 128; s > 0; s >>= 1) { if (tid < s) red[tid] += red[tid + s]; __syncthreads(); }
    float inv = 1.f / red[0];
    for (int i = tid; i < VV; i += 256) out[(size_t)r * VV + i] = expf(L[i] - m) * inv;
}

extern "C" void kernel_launch(void* const* d_in, const int* in_sizes, int n_in,
                              void* d_out, int out_size, void* d_ws, size_t ws_size,
                              hipStream_t stream) {
    const int*   x    = (const int*)  d_in[0];
    const float* tab  = (const float*)d_in[1];
    const float* Wx0  = (const float*)d_in[2];
    const float* Wh0  = (const float*)d_in[3];
    const float* b0   = (const float*)d_in[4];
    const float* Wx1  = (const float*)d_in[5];
    const float* Wh1  = (const float*)d_in[6];
    const float* b1   = (const float*)d_in[7];
    const float* Wout = (const float*)d_in[8];
    const float* bout = (const float*)d_in[9];
    float* out = (float*)d_out;

    // ---- workspace layout (ushort units unless noted); all 16B aligned ----
    unsigned short* ws    = (unsigned short*)d_ws;
    unsigned short* embA  = ws;                    // 2048*16*512  = 16,777,216
    unsigned short* wx0p  = embA  + 16777216;      // 256*16*512   =  2,097,152
    unsigned short* wh0p  = wx0p  + 2097152;       // 256*32*512   =  4,194,304
    unsigned short* wx1p  = wh0p  + 4194304;       //              =  4,194,304
    unsigned short* wh1p  = wx1p  + 4194304;       //              =  4,194,304
    unsigned short* woutp = wh1p  + 4194304;       // 2000*32*512  = 32,768,000
    unsigned short* x4    = woutp + 32768000;      // 32768*4096   = 134,217,728
    unsigned short* h1A   = x4    + 134217728;     // 2048*32*512  = 33,554,432
    unsigned short* hb0   = h1A   + 33554432;      // 65,536
    unsigned short* hb1   = hb0   + 65536;         // 65,536
    float* cbuf   = (float*)(hb1 + 65536);         // 65,536 f32
    float* logits = cbuf + 65536;                  // 2,048,000 f32
    // total ~474 MB

    // ---- weight packing (per launch; inputs are restored each call) ----
    pack_b<<<256 * 16, 64, 0, stream>>>(Wx0, wx0p, 16, GG);
    pack_b<<<256 * 32, 64, 0, stream>>>(Wh0, wh0p, 32, GG);
    pack_b<<<256 * 32, 64, 0, stream>>>(Wx1, wx1p, 32, GG);
    pack_b<<<256 * 32, 64, 0, stream>>>(Wh1, wh1p, 32, GG);
    pack_b<<<2000 * 32, 64, 0, stream>>>(Wout, woutp, 32, VV);

    // ---- embedding (packed-A) + layer-0 input projection ----
    embed_pack<<<32768, 64, 0, stream>>>(x, tab, embA);
    gemm_bias<1><<<dim3(GG / 64, 32768 / 64), 256, 0, stream>>>(embA, wx0p, b0, x4, GG, EE / 32);

    // ---- layer 0 recurrence ----
    zero_state<<<64, 256, 0, stream>>>(cbuf, hb0);
    for (int t = 0; t < SS; ++t)
        lstm_step<<<64, 256, 0, stream>>>(x4, wh0p, (t & 1) ? hb1 : hb0,
                                          (t & 1) ? hb0 : hb1, cbuf, h1A, t);

    // ---- layer 1 input projection + recurrence ----
    gemm_bias<1><<<dim3(GG / 64, 32768 / 64), 256, 0, stream>>>(h1A, wx1p, b1, x4, GG, HH / 32);
    zero_state<<<64, 256, 0, stream>>>(cbuf, hb0);
    for (int t = 0; t < SS; ++t)
        lstm_step<<<64, 256, 0, stream>>>(x4, wh1p, (t & 1) ? hb1 : hb0,
                                          (t & 1) ? hb0 : hb1, cbuf, nullptr, t);
    // after t=511 the new state is in hb0

    // ---- logits (last timestep only) + softmax ----
    gemm_bias<0><<<dim3(VV / 64, 1), 256, 0, stream>>>(hb0, woutp, bout, logits, VV, HH / 32);
    softmax_rows<<<64, 256, 0, stream>>>(logits, out);
}